// Round 10
// baseline (556.094 us; speedup 1.0000x reference)
//
#include <hip/hip_runtime.h>
#include <hip/hip_bf16.h>
#include <hip/hip_fp16.h>
#include <math.h>
#include <stdint.h>

#define BB 128
#define SS 256
#define EE 256
#define HH 256
#define G4 1024
#define OUT_HEAD (BB*SS*2*HH)
#define SE 0.10825317547305482f   /* sqrt(3/256) embedding init bound */

// ws layout (bytes):
//  P8 int8-packed weights as uint32[64][1024] per matrix (256 KB each):
//   0      : hh_f    256K: hh_b    512K: ih_f    768K: ih_b
//  1M      : scales float[4][1024]  (hh_f, hh_b, ih_f, ih_b)
//  1.25M   : ints: perm[128], slen[128], qofr[128], olp[128], fdst[128*256], bdst[128*256]
//  4M      : gx fp16 [2][128][256][1024]  (128 MiB)
#define P8_HH_F 0
#define P8_HH_B 65536
#define P8_IH_F 131072
#define P8_IH_B 196608
#define SC_OFF  (1024*1024)
#define INT_OFF (1280*1024)
#define GX_OFF  (4*1024*1024)

__device__ __forceinline__ float sigf(float x){ return 1.0f/(1.0f+__expf(-x)); }
__device__ __forceinline__ float tanhx(float x){
    float t = __expf(2.0f*x);
    return 1.0f - 2.0f/(t+1.0f);
}
__device__ __forceinline__ int dot4(uint32_t a, uint32_t b, int acc){
    return __builtin_amdgcn_sdot4((int)a, (int)b, acc, false);
}

// One wave per gate-row: quantize row g of a (1024,256) fp32 matrix to int8
// with per-row scale. P8[j*1024+g] packs W[g][4j..4j+3]; SC[g] = wmax/127.
__global__ __launch_bounds__(64) void pack8(const float* __restrict__ W,
    uint32_t* __restrict__ P8, float* __restrict__ SC){
    const int g = blockIdx.x, lane = threadIdx.x;
    float4 w4 = ((const float4*)(W + (size_t)g*EE))[lane];
    float m = fmaxf(fmaxf(fabsf(w4.x), fabsf(w4.y)), fmaxf(fabsf(w4.z), fabsf(w4.w)));
    for(int off=32; off; off>>=1) m = fmaxf(m, __shfl_xor(m, off));
    const float inv = (m > 0.f) ? 127.f/m : 0.f;
    int b0 = (int)rintf(w4.x*inv), b1 = (int)rintf(w4.y*inv);
    int b2 = (int)rintf(w4.z*inv), b3 = (int)rintf(w4.w*inv);
    uint32_t p = (uint32_t)(b0 & 0xff) | ((uint32_t)(b1 & 0xff) << 8) |
                 ((uint32_t)(b2 & 0xff) << 16) | ((uint32_t)(b3 & 0xff) << 24);
    P8[lane*G4 + g] = p;
    if(lane == 0) SC[g] = m / 127.f;
}

// Single-block prep: lengths, stable ranks, scatter dests (verified R3/R5/R7).
__global__ void prep(const int* __restrict__ sw, const int* __restrict__ fm,
                     const int* __restrict__ bm, int* __restrict__ wsI,
                     float* __restrict__ out_tail){
    __shared__ int len_s[BB], flen_s[BB], perm_s[BB], olp_s[BB];
    int b = threadIdx.x;
    int cnt = 0, fcnt = 0;
    for(int t=0;t<SS;t++){
        cnt  += (sw[b*SS+t] != 0);
        fcnt += fm[b*SS+t];
    }
    len_s[b] = cnt; flen_s[b] = fcnt;
    __syncthreads();
    int r = 0;
    for(int b2=0;b2<BB;b2++){
        int l2 = len_s[b2];
        r += (l2 > cnt) || (l2 == cnt && b2 < b);
    }
    perm_s[r] = b;
    __syncthreads();
    int orig = perm_s[b];
    olp_s[b] = flen_s[orig];
    wsI[0*BB + b] = orig;
    wsI[1*BB + b] = len_s[orig];
    __syncthreads();
    int v = olp_s[b];
    int q = 0;
    for(int r2=0;r2<BB;r2++){
        int v2 = olp_s[r2];
        q += (v2 > v) || (v2 == v && r2 < b);
    }
    wsI[2*BB + b] = q;
    wsI[3*BB + b] = v;
    out_tail[q] = (float)v;
    int* fdst = wsI + 4*BB;
    int* bdst = fdst + BB*SS;
    int fc = 0, bc = 0;
    for(int t=0;t<SS;t++){
        int fv = fm[orig*SS+t];
        fdst[b*SS+t] = (fv && fc < v) ? (q*SS + fc) : -1;
        fc += fv;
        int bv = bm[orig*SS+t];
        bdst[b*SS+t] = (bv && bc < v) ? (q*SS + bc) : -1;
        bc += bv;
    }
}

// x-pass, int8 weight-resident: gx[dir][r][t][g] = bias[g] + x_t . Wih[g]
// 1024 threads, thread g owns gate-row g: 64 weight dwords in VGPRs.
// Loads are VOLATILE: R7-R9 showed invariant/noclobber loads get sunk or
// rematerialized into the step loop (VGPR=44/52, ~2600cyc/step of L2 traffic);
// volatile forbids duplication/sinking, so the values must stay live.
__global__ __launch_bounds__(1024)
__attribute__((amdgpu_waves_per_eu(4,4)))
void xg8(const int* __restrict__ sw,
    const float* __restrict__ emb, const float* __restrict__ b_f,
    const float* __restrict__ b_b, const uint32_t* __restrict__ wsU,
    const float* __restrict__ scl, const int* __restrict__ wsI,
    _Float16* __restrict__ gx){
    __shared__ int x8i[64];
    const int tid = threadIdx.x, r = blockIdx.x, dir = blockIdx.y;
    const volatile uint32_t* P = wsU + (dir ? P8_IH_B : P8_IH_F);
    uint32_t w[64];
    #pragma unroll
    for(int j=0;j<64;j++) w[j] = P[j*G4 + tid];
    #pragma unroll
    for(int j=0;j<64;j++) asm volatile("" : "+v"(w[j]));
    const float cs = scl[(2 + dir)*G4 + tid] * (SE/127.f);
    const float bias = (dir ? b_b : b_f)[tid];
    const int orig = wsI[r], L = wsI[BB + r];
    const int* ids = sw + orig*SS;
    float xv = 0.f;
    if(tid < EE) xv = emb[(size_t)ids[0]*EE + tid];
    _Float16* gxr = gx + ((size_t)(dir*BB + r))*SS*G4;

    for(int t=0;t<L;t++){
        if(tid < EE) ((signed char*)x8i)[tid] = (signed char)(int)rintf(xv*(127.f/SE));
        __syncthreads();
        if(tid < EE && t+1 < L) xv = emb[(size_t)ids[t+1]*EE + tid];
        int acc0 = 0, acc1 = 0;
        const uint4* hp = (const uint4*)x8i;
        #pragma unroll
        for(int j=0;j<16;j++){
            uint4 hv = hp[j];
            acc0 = dot4(w[4*j+0], hv.x, acc0);
            acc1 = dot4(w[4*j+1], hv.y, acc1);
            acc0 = dot4(w[4*j+2], hv.z, acc0);
            acc1 = dot4(w[4*j+3], hv.w, acc1);
        }
        gxr[(size_t)t*G4 + tid] = (_Float16)(bias + (float)(acc0 + acc1)*cs);
        __syncthreads();
    }
}

// Recurrent pass, int8 weight-resident: thread g owns gate-row g of Whh,
// 64 weight dwords held live via volatile loads + asm pin.
__global__ __launch_bounds__(1024)
__attribute__((amdgpu_waves_per_eu(4,4)))
void rec8(const uint32_t* __restrict__ wsU,
    const float* __restrict__ scl, const int* __restrict__ wsI,
    const _Float16* __restrict__ gx, float* __restrict__ out){
    __shared__ int h8i[64];
    __shared__ float gfl[G4];
    const int tid = threadIdx.x, r = blockIdx.x, dir = blockIdx.y;
    const volatile uint32_t* P = wsU + (dir ? P8_HH_B : P8_HH_F);
    uint32_t w[64];
    #pragma unroll
    for(int j=0;j<64;j++) w[j] = P[j*G4 + tid];
    #pragma unroll
    for(int j=0;j<64;j++) asm volatile("" : "+v"(w[j]));
    const float csh = scl[dir*G4 + tid] * (1.f/127.f);
    const int L = wsI[BB + r];
    const int* dstA = wsI + 4*BB + (dir ? BB*SS : 0) + r*SS;
    if(tid < 64) h8i[tid] = 0;
    float cst = 0.f;
    const _Float16* gxr = gx + ((size_t)(dir*BB + r))*SS*G4;
    const int t0 = dir ? L-1 : 0, stp = dir ? -1 : 1;
    _Float16 gv = gxr[(size_t)t0*G4 + tid];
    __syncthreads();

    for(int s=0;s<L;s++){
        const int t = t0 + s*stp;
        const float gxv = (float)gv;
        if(s+1 < L) gv = gxr[(size_t)(t+stp)*G4 + tid];
        int acc0 = 0, acc1 = 0;
        const uint4* hp = (const uint4*)h8i;
        #pragma unroll
        for(int j=0;j<16;j++){
            uint4 hv = hp[j];
            acc0 = dot4(w[4*j+0], hv.x, acc0);
            acc1 = dot4(w[4*j+1], hv.y, acc1);
            acc0 = dot4(w[4*j+2], hv.z, acc0);
            acc1 = dot4(w[4*j+3], hv.w, acc1);
        }
        gfl[tid] = gxv + (float)(acc0 + acc1)*csh;
        __syncthreads();
        if(tid < HH){
            float gi = gfl[tid], gf = gfl[tid+256], gz = gfl[tid+512], go = gfl[tid+768];
            float i = sigf(gi), f = sigf(gf), z = tanhx(gz), o = sigf(go);
            cst = f*cst + i*z;
            float hn = o*tanhx(cst);
            ((signed char*)h8i)[tid] = (signed char)(int)rintf(hn*127.f);
            int dst = dstA[t];
            if(dst >= 0) out[(size_t)dst*(2*HH) + dir*HH + tid] = hn;
        }
        __syncthreads();
    }
}

extern "C" void kernel_launch(void* const* d_in, const int* in_sizes, int n_in,
                              void* d_out, int out_size, void* d_ws, size_t ws_size,
                              hipStream_t stream){
    const int*   sw    = (const int*)d_in[0];
    const int*   fm    = (const int*)d_in[1];
    const int*   bm    = (const int*)d_in[2];
    const float* emb   = (const float*)d_in[3];
    const float* Wih_f = (const float*)d_in[4];
    const float* Whh_f = (const float*)d_in[5];
    const float* b_f   = (const float*)d_in[6];
    const float* Wih_b = (const float*)d_in[7];
    const float* Whh_b = (const float*)d_in[8];
    const float* b_b   = (const float*)d_in[9];
    float* out = (float*)d_out;
    uint32_t* wsU = (uint32_t*)d_ws;
    float* scl = (float*)((char*)d_ws + SC_OFF);
    int* wsI = (int*)((char*)d_ws + INT_OFF);
    _Float16* gxp = (_Float16*)((char*)d_ws + GX_OFF);

    hipMemsetAsync(d_out, 0, (size_t)out_size*4, stream);
    pack8<<<G4, 64, 0, stream>>>(Whh_f, wsU + P8_HH_F, scl + 0*G4);
    pack8<<<G4, 64, 0, stream>>>(Whh_b, wsU + P8_HH_B, scl + 1*G4);
    pack8<<<G4, 64, 0, stream>>>(Wih_f, wsU + P8_IH_F, scl + 2*G4);
    pack8<<<G4, 64, 0, stream>>>(Wih_b, wsU + P8_IH_B, scl + 3*G4);
    prep<<<1, BB, 0, stream>>>(sw, fm, bm, wsI, out + OUT_HEAD);
    xg8<<<dim3(BB,2), 1024, 0, stream>>>(sw, emb, b_f, b_b, wsU, scl, wsI, gxp);
    rec8<<<dim3(BB,2), 1024, 0, stream>>>(wsU, scl, wsI, gxp, out);
}

// Round 11
// 519.509 us; speedup vs baseline: 1.0704x; 1.0704x over previous
//
#include <hip/hip_runtime.h>
#include <hip/hip_bf16.h>
#include <hip/hip_fp16.h>
#include <math.h>
#include <stdint.h>

#define BB 128
#define SS 256
#define EE 256
#define HH 256
#define G4 1024
#define OUT_HEAD (BB*SS*2*HH)
#define SE 0.10825317547305482f   /* sqrt(3/256) embedding init bound */

// ws layout (bytes):
//  int8 weights as uint32[65536] per matrix (256 KB each):
//   0: hh_f [g][j] (g-major, contiguous per gate row, for rec asm dwordx4)
//   256K: hh_b [g][j]
//   512K: ih_f [j][g] (j-major, coalesced per-j, for xg token-batched reload)
//   768K: ih_b [j][g]
//  1M: scales float[4][1024] (hh_f, hh_b, ih_f, ih_b)
//  1.25M: ints: perm[128], slen[128], qofr[128], olp[128], fdst[128*256], bdst[128*256]
//  4M: gx fp16 [2][128][256][1024]  (128 MiB)
#define P8_HH_F 0
#define P8_HH_B 65536
#define P8_IH_F 131072
#define P8_IH_B 196608
#define SC_OFF  (1024*1024)
#define INT_OFF (1280*1024)
#define GX_OFF  (4*1024*1024)

typedef uint32_t u32x4 __attribute__((ext_vector_type(4)));

__device__ __forceinline__ float sigf(float x){ return 1.0f/(1.0f+__expf(-x)); }
__device__ __forceinline__ float tanhx(float x){
    float t = __expf(2.0f*x);
    return 1.0f - 2.0f/(t+1.0f);
}
__device__ __forceinline__ int dot4(uint32_t a, uint32_t b, int acc){
    return __builtin_amdgcn_sdot4((int)a, (int)b, acc, false);
}

// One wave per gate-row: quantize row g of (1024,256) fp32 to int8, per-row scale.
// gmajor=1: P8[g*64+lane] (contiguous per row); gmajor=0: P8[lane*1024+g].
__global__ __launch_bounds__(64) void pack8(const float* __restrict__ W,
    uint32_t* __restrict__ P8, float* __restrict__ SC, int gmajor){
    const int g = blockIdx.x, lane = threadIdx.x;
    float4 w4 = ((const float4*)(W + (size_t)g*EE))[lane];
    float m = fmaxf(fmaxf(fabsf(w4.x), fabsf(w4.y)), fmaxf(fabsf(w4.z), fabsf(w4.w)));
    for(int off=32; off; off>>=1) m = fmaxf(m, __shfl_xor(m, off));
    const float inv = (m > 0.f) ? 127.f/m : 0.f;
    int b0 = (int)rintf(w4.x*inv), b1 = (int)rintf(w4.y*inv);
    int b2 = (int)rintf(w4.z*inv), b3 = (int)rintf(w4.w*inv);
    uint32_t p = (uint32_t)(b0 & 0xff) | ((uint32_t)(b1 & 0xff) << 8) |
                 ((uint32_t)(b2 & 0xff) << 16) | ((uint32_t)(b3 & 0xff) << 24);
    if(gmajor) P8[g*64 + lane] = p;
    else       P8[lane*G4 + g] = p;
    if(lane == 0) SC[g] = m / 127.f;
}

// Single-block prep: lengths, stable ranks, scatter dests (verified R3/R5/R7).
__global__ void prep(const int* __restrict__ sw, const int* __restrict__ fm,
                     const int* __restrict__ bm, int* __restrict__ wsI,
                     float* __restrict__ out_tail){
    __shared__ int len_s[BB], flen_s[BB], perm_s[BB], olp_s[BB];
    int b = threadIdx.x;
    int cnt = 0, fcnt = 0;
    for(int t=0;t<SS;t++){
        cnt  += (sw[b*SS+t] != 0);
        fcnt += fm[b*SS+t];
    }
    len_s[b] = cnt; flen_s[b] = fcnt;
    __syncthreads();
    int r = 0;
    for(int b2=0;b2<BB;b2++){
        int l2 = len_s[b2];
        r += (l2 > cnt) || (l2 == cnt && b2 < b);
    }
    perm_s[r] = b;
    __syncthreads();
    int orig = perm_s[b];
    olp_s[b] = flen_s[orig];
    wsI[0*BB + b] = orig;
    wsI[1*BB + b] = len_s[orig];
    __syncthreads();
    int v = olp_s[b];
    int q = 0;
    for(int r2=0;r2<BB;r2++){
        int v2 = olp_s[r2];
        q += (v2 > v) || (v2 == v && r2 < b);
    }
    wsI[2*BB + b] = q;
    wsI[3*BB + b] = v;
    out_tail[q] = (float)v;
    int* fdst = wsI + 4*BB;
    int* bdst = fdst + BB*SS;
    int fc = 0, bc = 0;
    for(int t=0;t<SS;t++){
        int fv = fm[orig*SS+t];
        fdst[b*SS+t] = (fv && fc < v) ? (q*SS + fc) : -1;
        fc += fv;
        int bv = bm[orig*SS+t];
        bdst[b*SS+t] = (bv && bc < v) ? (q*SS + bc) : -1;
        bc += bv;
    }
}

// x-pass, token-batched: each weight reload serves 16 tokens (no residency needed).
// Thread g computes gate g for 16 tokens per sweep; weights [j][g] coalesced.
#define XDOT(k) { uint4 hv = xv[(k)*16 + j]; \
    a##k = dot4(w0, hv.x, a##k); a##k = dot4(w1, hv.y, a##k); \
    a##k = dot4(w2, hv.z, a##k); a##k = dot4(w3, hv.w, a##k); }
#define XST(k) if(t0 + (k) < L) gxr[(size_t)(t0+(k))*G4 + tid] = (_Float16)(bias + (float)a##k*cs);

__global__ __launch_bounds__(1024,4) void xg8t(const int* __restrict__ sw,
    const float* __restrict__ emb, const float* __restrict__ b_f,
    const float* __restrict__ b_b, const uint32_t* __restrict__ wsU,
    const float* __restrict__ scl, const int* __restrict__ wsI,
    _Float16* __restrict__ gx){
    __shared__ uint32_t xq[16*64];   // 16 tokens x 256 int8
    const int tid = threadIdx.x, r = blockIdx.x, dir = blockIdx.y;
    const uint32_t* P = wsU + (dir ? P8_IH_B : P8_IH_F);
    const float cs = scl[(2 + dir)*G4 + tid] * (SE/127.f);
    const float bias = (dir ? b_b : b_f)[tid];
    const int orig = wsI[r], L = wsI[BB + r];
    const int* ids = sw + orig*SS;
    _Float16* gxr = gx + ((size_t)(dir*BB + r))*SS*G4;
    const int k = tid >> 6;          // token within batch of 16
    const int e4 = (tid & 63);       // dword (4 elems) within token

    for(int t0 = 0; t0 < L; t0 += 16){
        int t = t0 + k;              // always <= 255, in bounds
        float4 xf = ((const float4*)(emb + (size_t)ids[t]*EE))[e4];
        int b0 = (int)rintf(xf.x*(127.f/SE)), b1 = (int)rintf(xf.y*(127.f/SE));
        int b2 = (int)rintf(xf.z*(127.f/SE)), b3 = (int)rintf(xf.w*(127.f/SE));
        xq[k*64 + e4] = (uint32_t)(b0 & 0xff) | ((uint32_t)(b1 & 0xff) << 8) |
                        ((uint32_t)(b2 & 0xff) << 16) | ((uint32_t)(b3 & 0xff) << 24);
        __syncthreads();
        int a0=0,a1=0,a2=0,a3=0,a4=0,a5=0,a6=0,a7=0;
        int a8=0,a9=0,a10=0,a11=0,a12=0,a13=0,a14=0,a15=0;
        const uint4* xv = (const uint4*)xq;
        for(int j=0;j<16;j++){
            uint32_t w0 = P[(4*j+0)*G4 + tid];
            uint32_t w1 = P[(4*j+1)*G4 + tid];
            uint32_t w2 = P[(4*j+2)*G4 + tid];
            uint32_t w3 = P[(4*j+3)*G4 + tid];
            XDOT(0) XDOT(1) XDOT(2) XDOT(3) XDOT(4) XDOT(5) XDOT(6) XDOT(7)
            XDOT(8) XDOT(9) XDOT(10) XDOT(11) XDOT(12) XDOT(13) XDOT(14) XDOT(15)
        }
        XST(0) XST(1) XST(2) XST(3) XST(4) XST(5) XST(6) XST(7)
        XST(8) XST(9) XST(10) XST(11) XST(12) XST(13) XST(14) XST(15)
        __syncthreads();
    }
}

// Recurrent pass: weights loaded via opaque inline-asm dwordx4 into 16 named
// quads (not remat-able, not sinkable); g-major layout so one base + imm offsets.
#define LDQ(name, o) u32x4 name; \
    asm volatile("global_load_dwordx4 %0, %1, off offset:" #o \
                 : "=v"(name) : "v"(bptr) : "memory");
#define PIN(name) asm volatile("" : "+v"(name));
#define DOTQ(q, hvv) { uint4 hv = hvv; \
    acc0 = dot4(q.x, hv.x, acc0); acc1 = dot4(q.y, hv.y, acc1); \
    acc0 = dot4(q.z, hv.z, acc0); acc1 = dot4(q.w, hv.w, acc1); }

__global__ __launch_bounds__(1024,4) void rec8(const uint32_t* __restrict__ wsU,
    const float* __restrict__ scl, const int* __restrict__ wsI,
    const _Float16* __restrict__ gx, float* __restrict__ out){
    __shared__ int h8i[64];
    __shared__ float gfl[G4];
    const int tid = threadIdx.x, r = blockIdx.x, dir = blockIdx.y;
    const uint32_t* bptr = wsU + (dir ? P8_HH_B : P8_HH_F) + (size_t)tid*64;
    LDQ(q0,0)    LDQ(q1,16)   LDQ(q2,32)   LDQ(q3,48)
    LDQ(q4,64)   LDQ(q5,80)   LDQ(q6,96)   LDQ(q7,112)
    LDQ(q8,128)  LDQ(q9,144)  LDQ(q10,160) LDQ(q11,176)
    LDQ(q12,192) LDQ(q13,208) LDQ(q14,224) LDQ(q15,240)
    asm volatile("s_waitcnt vmcnt(0)" ::: "memory");
    __builtin_amdgcn_sched_barrier(0);
    PIN(q0) PIN(q1) PIN(q2) PIN(q3) PIN(q4) PIN(q5) PIN(q6) PIN(q7)
    PIN(q8) PIN(q9) PIN(q10) PIN(q11) PIN(q12) PIN(q13) PIN(q14) PIN(q15)
    const float csh = scl[dir*G4 + tid] * (1.f/127.f);
    const int L = wsI[BB + r];
    const int* dstA = wsI + 4*BB + (dir ? BB*SS : 0) + r*SS;
    if(tid < 64) h8i[tid] = 0;
    float cst = 0.f;
    const _Float16* gxr = gx + ((size_t)(dir*BB + r))*SS*G4;
    const int t0 = dir ? L-1 : 0, stp = dir ? -1 : 1;
    _Float16 gv = gxr[(size_t)t0*G4 + tid];
    __syncthreads();

    for(int s=0;s<L;s++){
        const int t = t0 + s*stp;
        const float gxv = (float)gv;
        if(s+1 < L) gv = gxr[(size_t)(t+stp)*G4 + tid];
        int acc0 = 0, acc1 = 0;
        const uint4* hp = (const uint4*)h8i;
        DOTQ(q0,  hp[0])  DOTQ(q1,  hp[1])  DOTQ(q2,  hp[2])  DOTQ(q3,  hp[3])
        DOTQ(q4,  hp[4])  DOTQ(q5,  hp[5])  DOTQ(q6,  hp[6])  DOTQ(q7,  hp[7])
        DOTQ(q8,  hp[8])  DOTQ(q9,  hp[9])  DOTQ(q10, hp[10]) DOTQ(q11, hp[11])
        DOTQ(q12, hp[12]) DOTQ(q13, hp[13]) DOTQ(q14, hp[14]) DOTQ(q15, hp[15])
        gfl[tid] = gxv + (float)(acc0 + acc1)*csh;
        __syncthreads();
        if(tid < HH){
            float gi = gfl[tid], gf = gfl[tid+256], gz = gfl[tid+512], go = gfl[tid+768];
            float i = sigf(gi), f = sigf(gf), z = tanhx(gz), o = sigf(go);
            cst = f*cst + i*z;
            float hn = o*tanhx(cst);
            ((signed char*)h8i)[tid] = (signed char)(int)rintf(hn*127.f);
            int dst = dstA[t];
            if(dst >= 0) out[(size_t)dst*(2*HH) + dir*HH + tid] = hn;
        }
        __syncthreads();
    }
}

extern "C" void kernel_launch(void* const* d_in, const int* in_sizes, int n_in,
                              void* d_out, int out_size, void* d_ws, size_t ws_size,
                              hipStream_t stream){
    const int*   sw    = (const int*)d_in[0];
    const int*   fm    = (const int*)d_in[1];
    const int*   bm    = (const int*)d_in[2];
    const float* emb   = (const float*)d_in[3];
    const float* Wih_f = (const float*)d_in[4];
    const float* Whh_f = (const float*)d_in[5];
    const float* b_f   = (const float*)d_in[6];
    const float* Wih_b = (const float*)d_in[7];
    const float* Whh_b = (const float*)d_in[8];
    const float* b_b   = (const float*)d_in[9];
    float* out = (float*)d_out;
    uint32_t* wsU = (uint32_t*)d_ws;
    float* scl = (float*)((char*)d_ws + SC_OFF);
    int* wsI = (int*)((char*)d_ws + INT_OFF);
    _Float16* gxp = (_Float16*)((char*)d_ws + GX_OFF);

    hipMemsetAsync(d_out, 0, (size_t)out_size*4, stream);
    pack8<<<G4, 64, 0, stream>>>(Whh_f, wsU + P8_HH_F, scl + 0*G4, 1);
    pack8<<<G4, 64, 0, stream>>>(Whh_b, wsU + P8_HH_B, scl + 1*G4, 1);
    pack8<<<G4, 64, 0, stream>>>(Wih_f, wsU + P8_IH_F, scl + 2*G4, 0);
    pack8<<<G4, 64, 0, stream>>>(Wih_b, wsU + P8_IH_B, scl + 3*G4, 0);
    prep<<<1, BB, 0, stream>>>(sw, fm, bm, wsI, out + OUT_HEAD);
    xg8t<<<dim3(BB,2), 1024, 0, stream>>>(sw, emb, b_f, b_b, wsU, scl, wsI, gxp);
    rec8<<<dim3(BB,2), 1024, 0, stream>>>(wsU, scl, wsI, gxp, out);
}